// Round 1
// 138.861 us; speedup vs baseline: 1.0226x; 1.0226x over previous
//
#include <hip/hip_runtime.h>

// image (1,1024,1024) f32, x (16,1,1024,1024) f32, W_KL (9,1,3,3) f32, b_KL (9,) f32.
// y[b,h,w] = sum_{a,d} (conv(image,W_KL)[a*3+d][h,w] + b[a*3+d]) * x[b,h+a-1,w+d-1]
#define IH 1024
#define IW 1024
#define NB 16
#define BPB 4   // batches per block (gridDim.z = NB/BPB)

typedef float v4f __attribute__((ext_vector_type(4)));
typedef float v2f __attribute__((ext_vector_type(2)));

// Load the 3x6 window for 4 output px at (h, w0..w0+3) into win[3][6]:
// win[a][j] = plane[h+a-1][w0-1+j], zero-padded. Aligned vector loads only.
__device__ __forceinline__ void load_win(const float* __restrict__ plane,
                                         int h, int w0, float win[3][6]) {
#pragma unroll
    for (int a = 0; a < 3; ++a) {
        const int hh = h + a - 1;
        const bool rowok = (hh >= 0) & (hh < IH);
        const float* rowp = plane + (size_t)(rowok ? hh : 0) * IW;
        const v2f lv = *(const v2f*)(rowp + (w0 > 0 ? w0 - 2 : 0));      // [w0-2,w0-1]
        const v4f mv = *(const v4f*)(rowp + w0);                          // [w0..w0+3]
        const v2f rv = *(const v2f*)(rowp + (w0 + 4 < IW ? w0 + 4 : IW - 2)); // [w0+4,w0+5]
        const float fl = (rowok && w0 > 0)       ? lv.y : 0.f;
        const float fr = (rowok && w0 + 4 < IW)  ? rv.x : 0.f;
        win[a][0] = fl;
        win[a][1] = rowok ? mv.x : 0.f;
        win[a][2] = rowok ? mv.y : 0.f;
        win[a][3] = rowok ? mv.z : 0.f;
        win[a][4] = rowok ? mv.w : 0.f;
        win[a][5] = fr;
    }
}

// Block 64x4 = 256 thr; thread: 4 px at (h, w0..w0+3), BPB batches,
// software-pipelined (prefetch batch i+1's window while computing batch i).
// Grid (1024/256, 1024/4, NB/BPB) = (4,256,4) = 4096 blocks -> 16 blocks/CU,
// residency becomes VGPR-limited (~28 waves/CU) instead of grid-limited (16).
__global__ __launch_bounds__(256) void fused_smblock(
    const float* __restrict__ image,
    const float* __restrict__ x,
    const float* __restrict__ Wk,
    const float* __restrict__ bk,
    float* __restrict__ out)
{
    const int tx = threadIdx.x;               // 0..63
    const int ty = threadIdx.y;               // 0..3
    const int w0 = blockIdx.x * 256 + tx * 4; // float4-aligned
    const int h  = blockIdx.y * 4 + ty;
    const int b0 = blockIdx.z * BPB;

    // conv weights / bias: uniform addresses -> scalar loads (SGPRs)
    float wk[81];
#pragma unroll
    for (int i = 0; i < 81; ++i) wk[i] = Wk[i];
    float bb[9];
#pragma unroll
    for (int c = 0; c < 9; ++c) bb[c] = bk[c];

    const size_t plane = (size_t)IH * IW;
    const size_t obase = (size_t)h * IW + w0;
    const float* __restrict__ xb = x + (size_t)b0 * plane;

    // Issue image window AND batch b0's x window back-to-back; the K-phase
    // FMAs below only wait on the image loads (counted vmcnt), so batch b0's
    // HBM latency hides under the 324 K-FMAs.
    float p[3][6];
    load_win(image, h, w0, p);
    float buf[2][3][6];
    load_win(xb, h, w0, buf[0]);

    // ---- K phase: per-pixel kernels from image (amortized over BPB batches) ----
    float Kv[4][9];
#pragma unroll
    for (int j = 0; j < 4; ++j)
#pragma unroll
        for (int c = 0; c < 9; ++c) {
            float acc = bb[c];
#pragma unroll
            for (int a = 0; a < 3; ++a)
#pragma unroll
                for (int d = 0; d < 3; ++d)
                    acc = fmaf(wk[c * 9 + a * 3 + d], p[a][j + d], acc);
            Kv[j][c] = acc;
        }

    // ---- apply phase: depth-2 register pipeline over BPB batches ----
    float* __restrict__ ob = out + (size_t)b0 * plane + obase;
#pragma unroll
    for (int i = 0; i < BPB; ++i) {
        if (i + 1 < BPB)                      // issue batch i+1's loads first
            load_win(xb + (size_t)(i + 1) * plane, h, w0, buf[(i + 1) & 1]);
        const float (*r3)[6] = buf[i & 1];    // consume batch i
        v4f y;
#pragma unroll
        for (int j = 0; j < 4; ++j) {
            float acc = 0.f;
#pragma unroll
            for (int a = 0; a < 3; ++a)
#pragma unroll
                for (int d = 0; d < 3; ++d)
                    acc = fmaf(Kv[j][a * 3 + d], r3[a][j + d], acc);
            y[j] = acc;
        }
        __builtin_nontemporal_store(y, (v4f*)(ob + (size_t)i * plane));
    }
}

extern "C" void kernel_launch(void* const* d_in, const int* in_sizes, int n_in,
                              void* d_out, int out_size, void* d_ws, size_t ws_size,
                              hipStream_t stream) {
    const float* image = (const float*)d_in[0]; // 1*1024*1024
    const float* x     = (const float*)d_in[1]; // 16*1*1024*1024
    const float* Wk    = (const float*)d_in[2]; // 9*1*3*3
    const float* bk    = (const float*)d_in[3]; // 9
    float* out = (float*)d_out;                 // 16*1024*1024 f32

    dim3 block(64, 4);
    dim3 grid(IW / 256, IH / 4, NB / BPB);      // (4, 256, 4) = 4096 blocks
    fused_smblock<<<grid, block, 0, stream>>>(image, x, Wk, bk, out);
}